// Round 8
// baseline (559.613 us; speedup 1.0000x reference)
//
#include <hip/hip_runtime.h>

// GAT 3-layer forward — Round 8:
//  * deg_kernel XCD-partitioned (same as fill): each deg cacheline atomically
//    updated by one XCD only -> kills cross-XCD atomic line ping-pong.
//  * gathers: alpha (als-load+lrelu+exp) computed once per (edge,head) by a
//    single lane, octet-broadcast via __shfl(.,i,8). Bit-identical results,
//    ~40% hot-loop VALU cut (exp is quarter-rate transcendental).
//  * feat MFMA / scans / wcvt unchanged from round 7.
//
// Workspace (~66 MB):
//   bufXb u16[N*128] | HfB u16[N*128] | Wt0 u16[16384] | Wt1 u16[16384]
//   | Wt2 u16[8192] | als f32[N*8] | ald f32[N*8] | deg u32[N] | offs u32[N+1]
//   | cursor u32[N] | bsum u32[1024] | csr i32[E+N]

#define LRELU_SLOPE 0.2f
#define LN_EPS 1e-5f
typedef unsigned int u32;
typedef unsigned short u16;
typedef float f32x4 __attribute__((ext_vector_type(4)));
typedef short bf16x8 __attribute__((ext_vector_type(8)));

__device__ __forceinline__ u16 f2bf(float f) {  // RNE float->bf16
  u32 u = __float_as_uint(f);
  return (u16)((u + 0x7FFFu + ((u >> 16) & 1u)) >> 16);
}
__device__ __forceinline__ float bflo(u32 w) { return __uint_as_float(w << 16); }
__device__ __forceinline__ float bfhi(u32 w) { return __uint_as_float(w & 0xFFFF0000u); }
__device__ __forceinline__ float bf1(u16 w) { return __uint_as_float((u32)w << 16); }

// ========== W convert+transpose: Wt[c][k] = bf16(W[k][c]), once per call =====
__global__ void wcvt_kernel(const float* __restrict__ W0,
                            const float* __restrict__ W1,
                            const float* __restrict__ W2,
                            u16* __restrict__ Wt0, u16* __restrict__ Wt1,
                            u16* __restrict__ Wt2) {
  int i = blockIdx.x * 256 + threadIdx.x;
  if (i < 16384) {
    int k = i >> 7, c = i & 127;
    Wt0[c * 128 + k] = f2bf(W0[i]);
  } else if (i < 32768) {
    int j = i - 16384;
    int k = j >> 7, c = j & 127;
    Wt1[c * 128 + k] = f2bf(W1[j]);
  } else if (i < 40960) {
    int j = i - 32768;
    int k = j >> 6, c = j & 63;
    Wt2[c * 128 + k] = f2bf(W2[j]);
  }
}

// ========= feat (MFMA): H = X@W, bf16 out, fused als/ald dots ================
template <int DOUT, int NH, bool XBF>
__global__ __launch_bounds__(256) void feat_mfma(
    const void* __restrict__ Xv, const u16* __restrict__ Wtg,
    const float* __restrict__ As, const float* __restrict__ Ad,
    u16* __restrict__ HfB, float* __restrict__ als, float* __restrict__ ald,
    int n) {
  constexpr int NT = DOUT / 16;
  constexpr int XP = 136;        // +8 pad: 2-way banks, free
  __shared__ u16 Wl[DOUT * XP];
  __shared__ u16 Xl[64 * XP];
  __shared__ float AsL[DOUT], AdL[DOUT];

  const int tid = threadIdx.x;
  const int base = blockIdx.x * 64;

  if (tid < DOUT) { AsL[tid] = As[tid]; AdL[tid] = Ad[tid]; }
  for (int i = tid; i < DOUT * 16; i += 256) {
    int c = i >> 4, k0 = (i & 15) * 8;
    *(uint4*)&Wl[c * XP + k0] = *(const uint4*)&Wtg[c * 128 + k0];
  }
  for (int i = tid; i < 64 * 16; i += 256) {
    int r = i >> 4, k0 = (i & 15) * 8;
    int node = base + r;
    uint4 o = uint4{0, 0, 0, 0};
    if (node < n) {
      if (XBF) {
        o = *(const uint4*)((const u16*)Xv + (size_t)node * 128 + k0);
      } else {
        const float* Xf = (const float*)Xv;
        float4 v0 = *(const float4*)&Xf[(size_t)node * 128 + k0];
        float4 v1 = *(const float4*)&Xf[(size_t)node * 128 + k0 + 4];
        o.x = (u32)f2bf(v0.x) | ((u32)f2bf(v0.y) << 16);
        o.y = (u32)f2bf(v0.z) | ((u32)f2bf(v0.w) << 16);
        o.z = (u32)f2bf(v1.x) | ((u32)f2bf(v1.y) << 16);
        o.w = (u32)f2bf(v1.z) | ((u32)f2bf(v1.w) << 16);
      }
    }
    *(uint4*)&Xl[r * XP + k0] = o;
  }
  __syncthreads();

  const int w = tid >> 6, l = tid & 63;
  const int lr = l & 15, lg = l >> 4;
  f32x4 acc[NT];
#pragma unroll
  for (int t = 0; t < NT; ++t) acc[t] = f32x4{0.f, 0.f, 0.f, 0.f};

#pragma unroll
  for (int ks = 0; ks < 4; ++ks) {
    int kb = ks * 32 + lg * 8;
    bf16x8 a = *(const bf16x8*)&Xl[(w * 16 + lr) * XP + kb];
#pragma unroll
    for (int t = 0; t < NT; ++t) {
      bf16x8 b = *(const bf16x8*)&Wl[(t * 16 + lr) * XP + kb];
      acc[t] = __builtin_amdgcn_mfma_f32_16x16x32_bf16(a, b, acc[t], 0, 0, 0);
    }
  }

#pragma unroll
  for (int t = 0; t < NT; ++t)
#pragma unroll
    for (int j = 0; j < 4; ++j)
      Xl[(w * 16 + lg * 4 + j) * XP + t * 16 + lr] = f2bf(acc[t][j]);
  __syncthreads();

  for (int i = tid; i < 64 * (DOUT / 8); i += 256) {
    int r = i / (DOUT / 8), k0 = (i % (DOUT / 8)) * 8;
    int node = base + r;
    if (node < n)
      *(uint4*)&HfB[(size_t)node * DOUT + k0] = *(const uint4*)&Xl[r * XP + k0];
  }

  int row = tid >> 2, quad = tid & 3;
  int node = base + row;
  if (NH == 8) {
#pragma unroll
    for (int h2 = 0; h2 < 2; ++h2) {
      int h = quad * 2 + h2;
      float ps = 0.f, pd = 0.f;
#pragma unroll
      for (int i2 = 0; i2 < 16; ++i2) {
        float hv = bf1(Xl[row * XP + h * 16 + i2]);
        ps = fmaf(hv, AsL[h * 16 + i2], ps);
        pd = fmaf(hv, AdL[h * 16 + i2], pd);
      }
      if (node < n) {
        als[node * 8 + h] = ps;
        ald[node * 8 + h] = pd;
      }
    }
  } else {
    float ps = 0.f, pd = 0.f;
#pragma unroll
    for (int i2 = 0; i2 < 16; ++i2) {
      float hv = bf1(Xl[row * XP + quad * 16 + i2]);
      ps = fmaf(hv, AsL[quad * 16 + i2], ps);
      pd = fmaf(hv, AdL[quad * 16 + i2], pd);
    }
    ps += __shfl_xor(ps, 1, 64);
    ps += __shfl_xor(ps, 2, 64);
    pd += __shfl_xor(pd, 1, 64);
    pd += __shfl_xor(pd, 2, 64);
    if (quad == 0 && node < n) {
      als[node] = ps;
      ald[node] = pd;
    }
  }
}

// ================= CSR build (once per call, reused 3x) ======================
// XCD-partitioned histogram: block b -> dst slot (b&7), edge segment (b>>3).
// Each deg cacheline is atomically updated from a single XCD only.
__global__ __launch_bounds__(256) void deg_kernel(
    const int* __restrict__ ei, u32* __restrict__ deg, int E, int n,
    int nper, int chunk) {
  const int lo = (blockIdx.x & 7) * nper;
  const int hi = min(lo + nper, n);
  const int e0 = (blockIdx.x >> 3) * chunk;
  const int e1 = min(e0 + chunk, E + n);
  for (int e = e0 + (int)threadIdx.x; e < e1; e += 256) {
    int d = (e < E) ? ei[E + e] : (e - E);
    if (d >= lo && d < hi) atomicAdd(&deg[d], 1u);
  }
}

__global__ __launch_bounds__(1024) void scan1_kernel(const u32* __restrict__ deg,
                                                     u32* __restrict__ offs,
                                                     u32* __restrict__ bsum, int n) {
  __shared__ u32 tmp[1024];
  int t = threadIdx.x, i = blockIdx.x * 1024 + t;
  u32 v = (i < n) ? deg[i] : 0u;
  tmp[t] = v;
  __syncthreads();
  for (int off = 1; off < 1024; off <<= 1) {
    u32 a = (t >= off) ? tmp[t - off] : 0u;
    __syncthreads();
    tmp[t] += a;
    __syncthreads();
  }
  if (i < n) offs[i] = tmp[t] - v;
  if (t == 1023) bsum[blockIdx.x] = tmp[t];
}

__global__ __launch_bounds__(1024) void scan2_kernel(u32* __restrict__ bsum, int nb) {
  __shared__ u32 tmp[1024];
  int t = threadIdx.x;
  u32 v = (t < nb) ? bsum[t] : 0u;
  tmp[t] = v;
  __syncthreads();
  for (int off = 1; off < 1024; off <<= 1) {
    u32 a = (t >= off) ? tmp[t - off] : 0u;
    __syncthreads();
    tmp[t] += a;
    __syncthreads();
  }
  if (t < nb) bsum[t] = tmp[t] - v;
}

__global__ __launch_bounds__(1024) void scan3_kernel(u32* __restrict__ offs,
                                                     const u32* __restrict__ bsum,
                                                     u32* __restrict__ cursor,
                                                     int n, u32 total) {
  int i = blockIdx.x * 1024 + threadIdx.x;
  if (i < n) {
    u32 v = offs[i] + bsum[blockIdx.x];
    offs[i] = v;
    cursor[i] = v;
  }
  if (i == 0) offs[n] = total;
}

// XCD-partitioned fill (round 5): single-XCD ownership of csr/cursor lines.
__global__ __launch_bounds__(256) void fill_kernel(
    const int* __restrict__ ei, u32* __restrict__ cursor,
    int* __restrict__ csr_src, int E, int n, int nper, int chunk) {
  const int lo = (blockIdx.x & 7) * nper;
  const int hi = min(lo + nper, n);
  const int e0 = (blockIdx.x >> 3) * chunk;
  const int e1 = min(e0 + chunk, E + n);
  for (int e = e0 + (int)threadIdx.x; e < e1; e += 256) {
    int d = (e < E) ? ei[E + e] : (e - E);
    if (d >= lo && d < hi) {
      int s = (e < E) ? ei[e] : d;
      u32 pos = atomicAdd(&cursor[d], 1u);
      csr_src[pos] = s;
    }
  }
}

// ===== gather, DF=128, 8 heads, bf16 H, octet-broadcast alpha, LN+ReLU ======
__global__ __launch_bounds__(256) void gat_gather128(
    const u32* __restrict__ offs, const int* __restrict__ csr,
    const float* __restrict__ als, const float* __restrict__ ald,
    const u16* __restrict__ HfB, const float* __restrict__ bias,
    const float* __restrict__ g, const float* __restrict__ b,
    u16* __restrict__ outp, int n) {
  int d = blockIdx.x * 4 + (threadIdx.x >> 6);
  if (d >= n) return;
  const int lane = threadIdx.x & 63;
  const int h = lane >> 3;
  const float adv = ald[d * 8 + h];
  const u32* HfW = (const u32*)HfB;
  float accA = 0.f, accB = 0.f, lsum = 0.f;

  u32 k0 = offs[d], k1 = offs[d + 1], k = k0;
  for (; k + 8 <= k1; k += 8) {
    int s[8];
#pragma unroll
    for (int i = 0; i < 8; ++i) s[i] = csr[k + i];
    u32 w[8];
#pragma unroll
    for (int i = 0; i < 8; ++i) w[i] = HfW[(u32)s[i] * 64 + lane];
    // one alpha per lane: edge = lane&7, head = lane>>3 (my own head)
    int smine = csr[k + (lane & 7)];
    float v = als[smine * 8 + h] + adv;
    v = fmaxf(v, LRELU_SLOPE * v);
    float pm = __expf(v);
#pragma unroll
    for (int i = 0; i < 8; ++i) {
      float p = __shfl(pm, i, 8);  // octet-local broadcast
      lsum += p;
      accA = fmaf(p, bflo(w[i]), accA);
      accB = fmaf(p, bfhi(w[i]), accB);
    }
  }
  if (k + 4 <= k1) {
    int s[4];
    float a[4];
    u32 w[4];
#pragma unroll
    for (int i = 0; i < 4; ++i) s[i] = csr[k + i];
#pragma unroll
    for (int i = 0; i < 4; ++i) {
      a[i] = als[s[i] * 8 + h];
      w[i] = HfW[(u32)s[i] * 64 + lane];
    }
#pragma unroll
    for (int i = 0; i < 4; ++i) {
      float v = a[i] + adv;
      v = fmaxf(v, LRELU_SLOPE * v);
      float p = __expf(v);
      lsum += p;
      accA = fmaf(p, bflo(w[i]), accA);
      accB = fmaf(p, bfhi(w[i]), accB);
    }
    k += 4;
  }
  for (; k < k1; ++k) {
    int s = csr[k];
    float aa = als[s * 8 + h];
    u32 w = HfW[(u32)s * 64 + lane];
    float v = aa + adv;
    v = fmaxf(v, LRELU_SLOPE * v);
    float p = __expf(v);
    lsum += p;
    accA = fmaf(p, bflo(w), accA);
    accB = fmaf(p, bfhi(w), accB);
  }

  float inv = 1.f / lsum;
  float2 bs = *(const float2*)&bias[2 * lane];
  float r0 = accA * inv + bs.x, r1 = accB * inv + bs.y;
  float ssum = r0 + r1;
#pragma unroll
  for (int off = 32; off > 0; off >>= 1) ssum += __shfl_xor(ssum, off, 64);
  float mu = ssum * (1.f / 128.f);
  float d0 = r0 - mu, d1 = r1 - mu;
  float q = d0 * d0 + d1 * d1;
#pragma unroll
  for (int off = 32; off > 0; off >>= 1) q += __shfl_xor(q, off, 64);
  float rstd = rsqrtf(q * (1.f / 128.f) + LN_EPS);
  float2 gg = *(const float2*)&g[2 * lane];
  float2 bb = *(const float2*)&b[2 * lane];
  float o0 = fmaxf(d0 * rstd * gg.x + bb.x, 0.f);
  float o1 = fmaxf(d1 * rstd * gg.y + bb.y, 0.f);
  u32 packed = (u32)f2bf(o0) | ((u32)f2bf(o1) << 16);
  *(u32*)&outp[(size_t)d * 128 + 2 * lane] = packed;
}

// ===== gather, DF=64, 1 head, bf16 H, octet-broadcast alpha, log_softmax ====
__global__ __launch_bounds__(256) void gat_gather64(
    const u32* __restrict__ offs, const int* __restrict__ csr,
    const float* __restrict__ als, const float* __restrict__ ald,
    const u16* __restrict__ HfB, const float* __restrict__ bias,
    float* __restrict__ outp, int n) {
  int d = blockIdx.x * 4 + (threadIdx.x >> 6);
  if (d >= n) return;
  const int lane = threadIdx.x & 63;
  const float adv = ald[d];
  float acc = 0.f, lsum = 0.f;
  u32 k0 = offs[d], k1 = offs[d + 1], k = k0;
  for (; k + 8 <= k1; k += 8) {
    int s[8];
#pragma unroll
    for (int i = 0; i < 8; ++i) s[i] = csr[k + i];
    u16 w[8];
#pragma unroll
    for (int i = 0; i < 8; ++i) w[i] = HfB[(size_t)s[i] * 64 + lane];
    // one alpha per octet-lane: edge = lane&7 (all octets compute same set)
    int smine = csr[k + (lane & 7)];
    float v = als[smine] + adv;
    v = fmaxf(v, LRELU_SLOPE * v);
    float pm = __expf(v);
#pragma unroll
    for (int i = 0; i < 8; ++i) {
      float p = __shfl(pm, i, 8);
      lsum += p;
      acc = fmaf(p, bf1(w[i]), acc);
    }
  }
  if (k + 4 <= k1) {
    int s[4];
    float a[4];
    u16 w[4];
#pragma unroll
    for (int i = 0; i < 4; ++i) s[i] = csr[k + i];
#pragma unroll
    for (int i = 0; i < 4; ++i) {
      a[i] = als[s[i]];
      w[i] = HfB[(size_t)s[i] * 64 + lane];
    }
#pragma unroll
    for (int i = 0; i < 4; ++i) {
      float v = a[i] + adv;
      v = fmaxf(v, LRELU_SLOPE * v);
      float p = __expf(v);
      lsum += p;
      acc = fmaf(p, bf1(w[i]), acc);
    }
    k += 4;
  }
  for (; k < k1; ++k) {
    int s = csr[k];
    float v = als[s] + adv;
    v = fmaxf(v, LRELU_SLOPE * v);
    float p = __expf(v);
    lsum += p;
    acc = fmaf(p, bf1(HfB[(size_t)s * 64 + lane]), acc);
  }
  float v = acc / lsum + bias[lane];
  float mx = v;
#pragma unroll
  for (int off = 32; off > 0; off >>= 1) mx = fmaxf(mx, __shfl_xor(mx, off, 64));
  float e = __expf(v - mx);
  float ssum = e;
#pragma unroll
  for (int off = 32; off > 0; off >>= 1) ssum += __shfl_xor(ssum, off, 64);
  outp[(size_t)d * 64 + lane] = v - mx - __logf(ssum);
}

// ============================== launch ======================================
extern "C" void kernel_launch(void* const* d_in, const int* in_sizes, int n_in,
                              void* d_out, int out_size, void* d_ws,
                              size_t ws_size, hipStream_t stream) {
  const float* x    = (const float*)d_in[0];
  const int*   ei   = (const int*)d_in[1];
  const float* W0   = (const float*)d_in[2];
  const float* as0  = (const float*)d_in[3];
  const float* ad0  = (const float*)d_in[4];
  const float* b0   = (const float*)d_in[5];
  const float* W1   = (const float*)d_in[6];
  const float* as1  = (const float*)d_in[7];
  const float* ad1  = (const float*)d_in[8];
  const float* b1   = (const float*)d_in[9];
  const float* W2   = (const float*)d_in[10];
  const float* as2  = (const float*)d_in[11];
  const float* ad2  = (const float*)d_in[12];
  const float* b2   = (const float*)d_in[13];
  const float* ln1g = (const float*)d_in[14];
  const float* ln1b = (const float*)d_in[15];
  const float* ln2g = (const float*)d_in[16];
  const float* ln2b = (const float*)d_in[17];

  const int n = in_sizes[0] / 128;
  const int E = in_sizes[1] / 2;
  const int EP = E + n;

  u16* bufXb = (u16*)d_ws;                        // N*128 bf16 (LN outputs)
  u16* HfB   = bufXb + (size_t)n * 128;           // N*128 bf16
  u16* Wt0   = HfB + (size_t)n * 128;             // 128*128
  u16* Wt1   = Wt0 + 16384;
  u16* Wt2   = Wt1 + 16384;                       // 64*128
  float* als = (float*)(Wt2 + 8192);              // N*8
  float* ald = als + (size_t)n * 8;
  u32* deg    = (u32*)(ald + (size_t)n * 8);
  u32* offs   = deg + n;
  u32* cursor = offs + (n + 1);
  u32* bsum   = cursor + n;
  int* csr    = (int*)(bsum + 1024);

  const dim3 blk(256);
  const int gFeat = (n + 63) / 64;
  const int gGath = (n + 3) / 4;
  const int nb = (n + 1023) / 1024;
  const int SEGS = 256;
  const int nper = (n + 7) / 8;
  const int chunk = (EP + SEGS - 1) / SEGS;

  // ---- CSR build + W convert ----
  hipMemsetAsync(deg, 0, (size_t)n * 4, stream);
  wcvt_kernel<<<160, blk, 0, stream>>>(W0, W1, W2, Wt0, Wt1, Wt2);
  deg_kernel<<<8 * SEGS, blk, 0, stream>>>(ei, deg, E, n, nper, chunk);
  scan1_kernel<<<nb, 1024, 0, stream>>>(deg, offs, bsum, n);
  scan2_kernel<<<1, 1024, 0, stream>>>(bsum, nb);
  scan3_kernel<<<nb, 1024, 0, stream>>>(offs, bsum, cursor, n, (u32)EP);
  fill_kernel<<<8 * SEGS, blk, 0, stream>>>(ei, cursor, csr, E, n, nper, chunk);

  // ---- conv0 + LN1 + ReLU ----
  feat_mfma<128, 8, false><<<gFeat, blk, 0, stream>>>(
      x, Wt0, as0, ad0, HfB, als, ald, n);
  gat_gather128<<<gGath, blk, 0, stream>>>(
      offs, csr, als, ald, HfB, b0, ln1g, ln1b, bufXb, n);

  // ---- conv1 + LN2 + ReLU ----
  feat_mfma<128, 8, true><<<gFeat, blk, 0, stream>>>(
      bufXb, Wt1, as1, ad1, HfB, als, ald, n);
  gat_gather128<<<gGath, blk, 0, stream>>>(
      offs, csr, als, ald, HfB, b1, ln2g, ln2b, bufXb, n);

  // ---- conv2 + log_softmax ----
  feat_mfma<64, 1, true><<<gFeat, blk, 0, stream>>>(
      bufXb, Wt2, as2, ad2, HfB, als, ald, n);
  gat_gather64<<<gGath, blk, 0, stream>>>(
      offs, csr, als, ald, HfB, b2, (float*)d_out, n);
}

// Round 9
// 529.303 us; speedup vs baseline: 1.0573x; 1.0573x over previous
//
#include <hip/hip_runtime.h>

// GAT 3-layer forward — Round 9:
//  * layers 0/1 gathered H stored fp8 e4m3 (hardware cvt both ways): halves the
//    dominant random-gather stream (256->128 B/edge). fp32 accumulation; als/ald
//    still fp32; quantization noise averages down over ~17-edge aggregation and
//    is renormalized by LN. Layer-2 H stays bf16 (feeds output logits).
//  * everything else identical to round 8.
//
// Workspace (~79 MB):
//   bufXb u16[N*128] | HfB u16[N*128] | Hf8 u8[N*128] | Wt0 u16[16384]
//   | Wt1 u16[16384] | Wt2 u16[8192] | als f32[N*8] | ald f32[N*8] | deg u32[N]
//   | offs u32[N+1] | cursor u32[N] | bsum u32[1024] | csr i32[E+N]

#define LRELU_SLOPE 0.2f
#define LN_EPS 1e-5f
typedef unsigned int u32;
typedef unsigned short u16;
typedef unsigned char u8;
typedef float f32x4 __attribute__((ext_vector_type(4)));
typedef short bf16x8 __attribute__((ext_vector_type(8)));

__device__ __forceinline__ u16 f2bf(float f) {  // RNE float->bf16
  u32 u = __float_as_uint(f);
  return (u16)((u + 0x7FFFu + ((u >> 16) & 1u)) >> 16);
}
__device__ __forceinline__ float bflo(u32 w) { return __uint_as_float(w << 16); }
__device__ __forceinline__ float bfhi(u32 w) { return __uint_as_float(w & 0xFFFF0000u); }
__device__ __forceinline__ float bf1(u16 w) { return __uint_as_float((u32)w << 16); }

// ========== W convert+transpose: Wt[c][k] = bf16(W[k][c]), once per call =====
__global__ void wcvt_kernel(const float* __restrict__ W0,
                            const float* __restrict__ W1,
                            const float* __restrict__ W2,
                            u16* __restrict__ Wt0, u16* __restrict__ Wt1,
                            u16* __restrict__ Wt2) {
  int i = blockIdx.x * 256 + threadIdx.x;
  if (i < 16384) {
    int k = i >> 7, c = i & 127;
    Wt0[c * 128 + k] = f2bf(W0[i]);
  } else if (i < 32768) {
    int j = i - 16384;
    int k = j >> 7, c = j & 127;
    Wt1[c * 128 + k] = f2bf(W1[j]);
  } else if (i < 40960) {
    int j = i - 32768;
    int k = j >> 6, c = j & 63;
    Wt2[c * 128 + k] = f2bf(W2[j]);
  }
}

// ========= feat (MFMA): H = X@W, bf16/fp8 out, fused als/ald dots ============
template <int DOUT, int NH, bool XBF, bool F8OUT>
__global__ __launch_bounds__(256) void feat_mfma(
    const void* __restrict__ Xv, const u16* __restrict__ Wtg,
    const float* __restrict__ As, const float* __restrict__ Ad,
    u16* __restrict__ HfB, u8* __restrict__ Hf8,
    float* __restrict__ als, float* __restrict__ ald, int n) {
  constexpr int NT = DOUT / 16;
  constexpr int XP = 136;        // +8 pad: 2-way banks, free
  __shared__ u16 Wl[DOUT * XP];
  __shared__ u16 Xl[64 * XP];
  __shared__ float AsL[DOUT], AdL[DOUT];

  const int tid = threadIdx.x;
  const int base = blockIdx.x * 64;

  if (tid < DOUT) { AsL[tid] = As[tid]; AdL[tid] = Ad[tid]; }
  for (int i = tid; i < DOUT * 16; i += 256) {
    int c = i >> 4, k0 = (i & 15) * 8;
    *(uint4*)&Wl[c * XP + k0] = *(const uint4*)&Wtg[c * 128 + k0];
  }
  for (int i = tid; i < 64 * 16; i += 256) {
    int r = i >> 4, k0 = (i & 15) * 8;
    int node = base + r;
    uint4 o = uint4{0, 0, 0, 0};
    if (node < n) {
      if (XBF) {
        o = *(const uint4*)((const u16*)Xv + (size_t)node * 128 + k0);
      } else {
        const float* Xf = (const float*)Xv;
        float4 v0 = *(const float4*)&Xf[(size_t)node * 128 + k0];
        float4 v1 = *(const float4*)&Xf[(size_t)node * 128 + k0 + 4];
        o.x = (u32)f2bf(v0.x) | ((u32)f2bf(v0.y) << 16);
        o.y = (u32)f2bf(v0.z) | ((u32)f2bf(v0.w) << 16);
        o.z = (u32)f2bf(v1.x) | ((u32)f2bf(v1.y) << 16);
        o.w = (u32)f2bf(v1.z) | ((u32)f2bf(v1.w) << 16);
      }
    }
    *(uint4*)&Xl[r * XP + k0] = o;
  }
  __syncthreads();

  const int w = tid >> 6, l = tid & 63;
  const int lr = l & 15, lg = l >> 4;
  f32x4 acc[NT];
#pragma unroll
  for (int t = 0; t < NT; ++t) acc[t] = f32x4{0.f, 0.f, 0.f, 0.f};

#pragma unroll
  for (int ks = 0; ks < 4; ++ks) {
    int kb = ks * 32 + lg * 8;
    bf16x8 a = *(const bf16x8*)&Xl[(w * 16 + lr) * XP + kb];
#pragma unroll
    for (int t = 0; t < NT; ++t) {
      bf16x8 b = *(const bf16x8*)&Wl[(t * 16 + lr) * XP + kb];
      acc[t] = __builtin_amdgcn_mfma_f32_16x16x32_bf16(a, b, acc[t], 0, 0, 0);
    }
  }

#pragma unroll
  for (int t = 0; t < NT; ++t)
#pragma unroll
    for (int j = 0; j < 4; ++j)
      Xl[(w * 16 + lg * 4 + j) * XP + t * 16 + lr] = f2bf(acc[t][j]);
  __syncthreads();

  if (F8OUT) {
    // fp8 e4m3 pack (hardware cvt) -> Hf8, 8 feats per thread-iter, 8B stores
    for (int i = tid; i < 64 * (DOUT / 8); i += 256) {
      int r = i / (DOUT / 8), c0 = (i % (DOUT / 8)) * 8;
      int node = base + r;
      if (node < n) {
        float f[8];
#pragma unroll
        for (int j = 0; j < 8; ++j) f[j] = bf1(Xl[r * XP + c0 + j]);
        int lo = 0, hi = 0;
        lo = __builtin_amdgcn_cvt_pk_fp8_f32(f[0], f[1], lo, false);
        lo = __builtin_amdgcn_cvt_pk_fp8_f32(f[2], f[3], lo, true);
        hi = __builtin_amdgcn_cvt_pk_fp8_f32(f[4], f[5], hi, false);
        hi = __builtin_amdgcn_cvt_pk_fp8_f32(f[6], f[7], hi, true);
        uint2 o = {(u32)lo, (u32)hi};
        *(uint2*)&Hf8[(size_t)node * DOUT + c0] = o;
      }
    }
  } else {
    for (int i = tid; i < 64 * (DOUT / 8); i += 256) {
      int r = i / (DOUT / 8), k0 = (i % (DOUT / 8)) * 8;
      int node = base + r;
      if (node < n)
        *(uint4*)&HfB[(size_t)node * DOUT + k0] = *(const uint4*)&Xl[r * XP + k0];
    }
  }

  int row = tid >> 2, quad = tid & 3;
  int node = base + row;
  if (NH == 8) {
#pragma unroll
    for (int h2 = 0; h2 < 2; ++h2) {
      int h = quad * 2 + h2;
      float ps = 0.f, pd = 0.f;
#pragma unroll
      for (int i2 = 0; i2 < 16; ++i2) {
        float hv = bf1(Xl[row * XP + h * 16 + i2]);
        ps = fmaf(hv, AsL[h * 16 + i2], ps);
        pd = fmaf(hv, AdL[h * 16 + i2], pd);
      }
      if (node < n) {
        als[node * 8 + h] = ps;
        ald[node * 8 + h] = pd;
      }
    }
  } else {
    float ps = 0.f, pd = 0.f;
#pragma unroll
    for (int i2 = 0; i2 < 16; ++i2) {
      float hv = bf1(Xl[row * XP + quad * 16 + i2]);
      ps = fmaf(hv, AsL[quad * 16 + i2], ps);
      pd = fmaf(hv, AdL[quad * 16 + i2], pd);
    }
    ps += __shfl_xor(ps, 1, 64);
    ps += __shfl_xor(ps, 2, 64);
    pd += __shfl_xor(pd, 1, 64);
    pd += __shfl_xor(pd, 2, 64);
    if (quad == 0 && node < n) {
      als[node] = ps;
      ald[node] = pd;
    }
  }
}

// ================= CSR build (once per call, reused 3x) ======================
__global__ __launch_bounds__(256) void deg_kernel(
    const int* __restrict__ ei, u32* __restrict__ deg, int E, int n,
    int nper, int chunk) {
  const int lo = (blockIdx.x & 7) * nper;
  const int hi = min(lo + nper, n);
  const int e0 = (blockIdx.x >> 3) * chunk;
  const int e1 = min(e0 + chunk, E + n);
  for (int e = e0 + (int)threadIdx.x; e < e1; e += 256) {
    int d = (e < E) ? ei[E + e] : (e - E);
    if (d >= lo && d < hi) atomicAdd(&deg[d], 1u);
  }
}

__global__ __launch_bounds__(1024) void scan1_kernel(const u32* __restrict__ deg,
                                                     u32* __restrict__ offs,
                                                     u32* __restrict__ bsum, int n) {
  __shared__ u32 tmp[1024];
  int t = threadIdx.x, i = blockIdx.x * 1024 + t;
  u32 v = (i < n) ? deg[i] : 0u;
  tmp[t] = v;
  __syncthreads();
  for (int off = 1; off < 1024; off <<= 1) {
    u32 a = (t >= off) ? tmp[t - off] : 0u;
    __syncthreads();
    tmp[t] += a;
    __syncthreads();
  }
  if (i < n) offs[i] = tmp[t] - v;
  if (t == 1023) bsum[blockIdx.x] = tmp[t];
}

__global__ __launch_bounds__(1024) void scan2_kernel(u32* __restrict__ bsum, int nb) {
  __shared__ u32 tmp[1024];
  int t = threadIdx.x;
  u32 v = (t < nb) ? bsum[t] : 0u;
  tmp[t] = v;
  __syncthreads();
  for (int off = 1; off < 1024; off <<= 1) {
    u32 a = (t >= off) ? tmp[t - off] : 0u;
    __syncthreads();
    tmp[t] += a;
    __syncthreads();
  }
  if (t < nb) bsum[t] = tmp[t] - v;
}

__global__ __launch_bounds__(1024) void scan3_kernel(u32* __restrict__ offs,
                                                     const u32* __restrict__ bsum,
                                                     u32* __restrict__ cursor,
                                                     int n, u32 total) {
  int i = blockIdx.x * 1024 + threadIdx.x;
  if (i < n) {
    u32 v = offs[i] + bsum[blockIdx.x];
    offs[i] = v;
    cursor[i] = v;
  }
  if (i == 0) offs[n] = total;
}

__global__ __launch_bounds__(256) void fill_kernel(
    const int* __restrict__ ei, u32* __restrict__ cursor,
    int* __restrict__ csr_src, int E, int n, int nper, int chunk) {
  const int lo = (blockIdx.x & 7) * nper;
  const int hi = min(lo + nper, n);
  const int e0 = (blockIdx.x >> 3) * chunk;
  const int e1 = min(e0 + chunk, E + n);
  for (int e = e0 + (int)threadIdx.x; e < e1; e += 256) {
    int d = (e < E) ? ei[E + e] : (e - E);
    if (d >= lo && d < hi) {
      int s = (e < E) ? ei[e] : d;
      u32 pos = atomicAdd(&cursor[d], 1u);
      csr_src[pos] = s;
    }
  }
}

// ===== gather, DF=128, 8 heads, fp8 H, octet-broadcast alpha, LN+ReLU =======
__global__ __launch_bounds__(256) void gat_gather128(
    const u32* __restrict__ offs, const int* __restrict__ csr,
    const float* __restrict__ als, const float* __restrict__ ald,
    const u8* __restrict__ Hf8, const float* __restrict__ bias,
    const float* __restrict__ g, const float* __restrict__ b,
    u16* __restrict__ outp, int n) {
  int d = blockIdx.x * 4 + (threadIdx.x >> 6);
  if (d >= n) return;
  const int lane = threadIdx.x & 63;
  const int h = lane >> 3;
  const float adv = ald[d * 8 + h];
  const u16* HfP = (const u16*)Hf8;  // pair of fp8 feats {2l,2l+1} at s*64+l
  float accA = 0.f, accB = 0.f, lsum = 0.f;

  u32 k0 = offs[d], k1 = offs[d + 1], k = k0;
  for (; k + 8 <= k1; k += 8) {
    int s[8];
#pragma unroll
    for (int i = 0; i < 8; ++i) s[i] = csr[k + i];
    u16 w[8];
#pragma unroll
    for (int i = 0; i < 8; ++i) w[i] = HfP[(u32)s[i] * 64 + lane];
    int smine = csr[k + (lane & 7)];
    float v = als[smine * 8 + h] + adv;
    v = fmaxf(v, LRELU_SLOPE * v);
    float pm = __expf(v);
#pragma unroll
    for (int i = 0; i < 8; ++i) {
      float p = __shfl(pm, i, 8);
      lsum += p;
      accA = fmaf(p, __builtin_amdgcn_cvt_f32_fp8((int)w[i], 0), accA);
      accB = fmaf(p, __builtin_amdgcn_cvt_f32_fp8((int)w[i], 1), accB);
    }
  }
  if (k + 4 <= k1) {
    int s[4];
    float a[4];
    u16 w[4];
#pragma unroll
    for (int i = 0; i < 4; ++i) s[i] = csr[k + i];
#pragma unroll
    for (int i = 0; i < 4; ++i) {
      a[i] = als[s[i] * 8 + h];
      w[i] = HfP[(u32)s[i] * 64 + lane];
    }
#pragma unroll
    for (int i = 0; i < 4; ++i) {
      float v = a[i] + adv;
      v = fmaxf(v, LRELU_SLOPE * v);
      float p = __expf(v);
      lsum += p;
      accA = fmaf(p, __builtin_amdgcn_cvt_f32_fp8((int)w[i], 0), accA);
      accB = fmaf(p, __builtin_amdgcn_cvt_f32_fp8((int)w[i], 1), accB);
    }
    k += 4;
  }
  for (; k < k1; ++k) {
    int s = csr[k];
    float aa = als[s * 8 + h];
    u16 w = HfP[(u32)s * 64 + lane];
    float v = aa + adv;
    v = fmaxf(v, LRELU_SLOPE * v);
    float p = __expf(v);
    lsum += p;
    accA = fmaf(p, __builtin_amdgcn_cvt_f32_fp8((int)w, 0), accA);
    accB = fmaf(p, __builtin_amdgcn_cvt_f32_fp8((int)w, 1), accB);
  }

  float inv = 1.f / lsum;
  float2 bs = *(const float2*)&bias[2 * lane];
  float r0 = accA * inv + bs.x, r1 = accB * inv + bs.y;
  float ssum = r0 + r1;
#pragma unroll
  for (int off = 32; off > 0; off >>= 1) ssum += __shfl_xor(ssum, off, 64);
  float mu = ssum * (1.f / 128.f);
  float d0 = r0 - mu, d1 = r1 - mu;
  float q = d0 * d0 + d1 * d1;
#pragma unroll
  for (int off = 32; off > 0; off >>= 1) q += __shfl_xor(q, off, 64);
  float rstd = rsqrtf(q * (1.f / 128.f) + LN_EPS);
  float2 gg = *(const float2*)&g[2 * lane];
  float2 bb = *(const float2*)&b[2 * lane];
  float o0 = fmaxf(d0 * rstd * gg.x + bb.x, 0.f);
  float o1 = fmaxf(d1 * rstd * gg.y + bb.y, 0.f);
  u32 packed = (u32)f2bf(o0) | ((u32)f2bf(o1) << 16);
  *(u32*)&outp[(size_t)d * 128 + 2 * lane] = packed;
}

// ===== gather, DF=64, 1 head, bf16 H, octet-broadcast alpha, log_softmax ====
__global__ __launch_bounds__(256) void gat_gather64(
    const u32* __restrict__ offs, const int* __restrict__ csr,
    const float* __restrict__ als, const float* __restrict__ ald,
    const u16* __restrict__ HfB, const float* __restrict__ bias,
    float* __restrict__ outp, int n) {
  int d = blockIdx.x * 4 + (threadIdx.x >> 6);
  if (d >= n) return;
  const int lane = threadIdx.x & 63;
  const float adv = ald[d];
  float acc = 0.f, lsum = 0.f;
  u32 k0 = offs[d], k1 = offs[d + 1], k = k0;
  for (; k + 8 <= k1; k += 8) {
    int s[8];
#pragma unroll
    for (int i = 0; i < 8; ++i) s[i] = csr[k + i];
    u16 w[8];
#pragma unroll
    for (int i = 0; i < 8; ++i) w[i] = HfB[(size_t)s[i] * 64 + lane];
    int smine = csr[k + (lane & 7)];
    float v = als[smine] + adv;
    v = fmaxf(v, LRELU_SLOPE * v);
    float pm = __expf(v);
#pragma unroll
    for (int i = 0; i < 8; ++i) {
      float p = __shfl(pm, i, 8);
      lsum += p;
      acc = fmaf(p, bf1(w[i]), acc);
    }
  }
  if (k + 4 <= k1) {
    int s[4];
    float a[4];
    u16 w[4];
#pragma unroll
    for (int i = 0; i < 4; ++i) s[i] = csr[k + i];
#pragma unroll
    for (int i = 0; i < 4; ++i) {
      a[i] = als[s[i]];
      w[i] = HfB[(size_t)s[i] * 64 + lane];
    }
#pragma unroll
    for (int i = 0; i < 4; ++i) {
      float v = a[i] + adv;
      v = fmaxf(v, LRELU_SLOPE * v);
      float p = __expf(v);
      lsum += p;
      acc = fmaf(p, bf1(w[i]), acc);
    }
    k += 4;
  }
  for (; k < k1; ++k) {
    int s = csr[k];
    float v = als[s] + adv;
    v = fmaxf(v, LRELU_SLOPE * v);
    float p = __expf(v);
    lsum += p;
    acc = fmaf(p, bf1(HfB[(size_t)s * 64 + lane]), acc);
  }
  float v = acc / lsum + bias[lane];
  float mx = v;
#pragma unroll
  for (int off = 32; off > 0; off >>= 1) mx = fmaxf(mx, __shfl_xor(mx, off, 64));
  float e = __expf(v - mx);
  float ssum = e;
#pragma unroll
  for (int off = 32; off > 0; off >>= 1) ssum += __shfl_xor(ssum, off, 64);
  outp[(size_t)d * 64 + lane] = v - mx - __logf(ssum);
}

// ============================== launch ======================================
extern "C" void kernel_launch(void* const* d_in, const int* in_sizes, int n_in,
                              void* d_out, int out_size, void* d_ws,
                              size_t ws_size, hipStream_t stream) {
  const float* x    = (const float*)d_in[0];
  const int*   ei   = (const int*)d_in[1];
  const float* W0   = (const float*)d_in[2];
  const float* as0  = (const float*)d_in[3];
  const float* ad0  = (const float*)d_in[4];
  const float* b0   = (const float*)d_in[5];
  const float* W1   = (const float*)d_in[6];
  const float* as1  = (const float*)d_in[7];
  const float* ad1  = (const float*)d_in[8];
  const float* b1   = (const float*)d_in[9];
  const float* W2   = (const float*)d_in[10];
  const float* as2  = (const float*)d_in[11];
  const float* ad2  = (const float*)d_in[12];
  const float* b2   = (const float*)d_in[13];
  const float* ln1g = (const float*)d_in[14];
  const float* ln1b = (const float*)d_in[15];
  const float* ln2g = (const float*)d_in[16];
  const float* ln2b = (const float*)d_in[17];

  const int n = in_sizes[0] / 128;
  const int E = in_sizes[1] / 2;
  const int EP = E + n;

  u16* bufXb = (u16*)d_ws;                        // N*128 bf16 (LN outputs)
  u16* HfB   = bufXb + (size_t)n * 128;           // N*128 bf16 (layer-2 H)
  u8*  Hf8   = (u8*)(HfB + (size_t)n * 128);      // N*128 fp8 (layers 0/1 H)
  u16* Wt0   = (u16*)(Hf8 + (size_t)n * 128);     // 128*128
  u16* Wt1   = Wt0 + 16384;
  u16* Wt2   = Wt1 + 16384;                       // 64*128
  float* als = (float*)(Wt2 + 8192);              // N*8
  float* ald = als + (size_t)n * 8;
  u32* deg    = (u32*)(ald + (size_t)n * 8);
  u32* offs   = deg + n;
  u32* cursor = offs + (n + 1);
  u32* bsum   = cursor + n;
  int* csr    = (int*)(bsum + 1024);

  const dim3 blk(256);
  const int gFeat = (n + 63) / 64;
  const int gGath = (n + 3) / 4;
  const int nb = (n + 1023) / 1024;
  const int SEGS = 256;
  const int nper = (n + 7) / 8;
  const int chunk = (EP + SEGS - 1) / SEGS;

  // ---- CSR build + W convert ----
  hipMemsetAsync(deg, 0, (size_t)n * 4, stream);
  wcvt_kernel<<<160, blk, 0, stream>>>(W0, W1, W2, Wt0, Wt1, Wt2);
  deg_kernel<<<8 * SEGS, blk, 0, stream>>>(ei, deg, E, n, nper, chunk);
  scan1_kernel<<<nb, 1024, 0, stream>>>(deg, offs, bsum, n);
  scan2_kernel<<<1, 1024, 0, stream>>>(bsum, nb);
  scan3_kernel<<<nb, 1024, 0, stream>>>(offs, bsum, cursor, n, (u32)EP);
  fill_kernel<<<8 * SEGS, blk, 0, stream>>>(ei, cursor, csr, E, n, nper, chunk);

  // ---- conv0 + LN1 + ReLU ----
  feat_mfma<128, 8, false, true><<<gFeat, blk, 0, stream>>>(
      x, Wt0, as0, ad0, HfB, Hf8, als, ald, n);
  gat_gather128<<<gGath, blk, 0, stream>>>(
      offs, csr, als, ald, Hf8, b0, ln1g, ln1b, bufXb, n);

  // ---- conv1 + LN2 + ReLU ----
  feat_mfma<128, 8, true, true><<<gFeat, blk, 0, stream>>>(
      bufXb, Wt1, as1, ad1, HfB, Hf8, als, ald, n);
  gat_gather128<<<gGath, blk, 0, stream>>>(
      offs, csr, als, ald, Hf8, b1, ln2g, ln2b, bufXb, n);

  // ---- conv2 + log_softmax (bf16 H, fp32 accum) ----
  feat_mfma<64, 1, true, false><<<gFeat, blk, 0, stream>>>(
      bufXb, Wt2, as2, ad2, HfB, Hf8, als, ald, n);
  gat_gather64<<<gGath, blk, 0, stream>>>(
      offs, csr, als, ald, HfB, b2, (float*)d_out, n);
}

// Round 10
// 523.826 us; speedup vs baseline: 1.0683x; 1.0105x over previous
//
#include <hip/hip_runtime.h>

// GAT 3-layer forward — Round 10:
//  * g128 inner loop on packed ops: cvt_pk_f32_fp8 (1 instr / 2 feats) and
//    f32x2 accumulator (packs to v_pk_fma_f32) -> ~24% wave-instruction cut.
//  * dispatch fusion: deg-zeroing folded into wcvt; scan2 merged into scan3
//    (per-block reduction of raw block sums). 13 -> 11 dispatches.
//  * everything else identical to round 9.
//
// Workspace (~79 MB): bufXb u16[N*128] | HfB u16[N*128] | Hf8 u8[N*128]
//   | Wt0/1/2 | als f32[N*8] | ald f32[N*8] | deg u32[N] | offs u32[N+1]
//   | cursor u32[N] | bsum u32[1024] | csr i32[E+N]

#define LRELU_SLOPE 0.2f
#define LN_EPS 1e-5f
typedef unsigned int u32;
typedef unsigned short u16;
typedef unsigned char u8;
typedef float f32x2 __attribute__((ext_vector_type(2)));
typedef float f32x4 __attribute__((ext_vector_type(4)));
typedef short bf16x8 __attribute__((ext_vector_type(8)));

__device__ __forceinline__ u16 f2bf(float f) {  // RNE float->bf16
  u32 u = __float_as_uint(f);
  return (u16)((u + 0x7FFFu + ((u >> 16) & 1u)) >> 16);
}
__device__ __forceinline__ float bf1(u16 w) { return __uint_as_float((u32)w << 16); }

// ==== W convert+transpose (+ deg zeroing fused), once per call ===============
__global__ void wcvt_kernel(const float* __restrict__ W0,
                            const float* __restrict__ W1,
                            const float* __restrict__ W2,
                            u16* __restrict__ Wt0, u16* __restrict__ Wt1,
                            u16* __restrict__ Wt2, u32* __restrict__ deg, int n) {
  int i = blockIdx.x * 256 + threadIdx.x;
  if (i < 16384) {
    int k = i >> 7, c = i & 127;
    Wt0[c * 128 + k] = f2bf(W0[i]);
  } else if (i < 32768) {
    int j = i - 16384;
    int k = j >> 7, c = j & 127;
    Wt1[c * 128 + k] = f2bf(W1[j]);
  } else if (i < 40960) {
    int j = i - 32768;
    int k = j >> 6, c = j & 63;
    Wt2[c * 128 + k] = f2bf(W2[j]);
  }
  for (int j = i; j < n; j += 40960) deg[j] = 0u;  // fused memset
}

// ========= feat (MFMA): H = X@W, bf16/fp8 out, fused als/ald dots ============
template <int DOUT, int NH, bool XBF, bool F8OUT>
__global__ __launch_bounds__(256) void feat_mfma(
    const void* __restrict__ Xv, const u16* __restrict__ Wtg,
    const float* __restrict__ As, const float* __restrict__ Ad,
    u16* __restrict__ HfB, u8* __restrict__ Hf8,
    float* __restrict__ als, float* __restrict__ ald, int n) {
  constexpr int NT = DOUT / 16;
  constexpr int XP = 136;        // +8 pad: 2-way banks, free
  __shared__ u16 Wl[DOUT * XP];
  __shared__ u16 Xl[64 * XP];
  __shared__ float AsL[DOUT], AdL[DOUT];

  const int tid = threadIdx.x;
  const int base = blockIdx.x * 64;

  if (tid < DOUT) { AsL[tid] = As[tid]; AdL[tid] = Ad[tid]; }
  for (int i = tid; i < DOUT * 16; i += 256) {
    int c = i >> 4, k0 = (i & 15) * 8;
    *(uint4*)&Wl[c * XP + k0] = *(const uint4*)&Wtg[c * 128 + k0];
  }
  for (int i = tid; i < 64 * 16; i += 256) {
    int r = i >> 4, k0 = (i & 15) * 8;
    int node = base + r;
    uint4 o = uint4{0, 0, 0, 0};
    if (node < n) {
      if (XBF) {
        o = *(const uint4*)((const u16*)Xv + (size_t)node * 128 + k0);
      } else {
        const float* Xf = (const float*)Xv;
        float4 v0 = *(const float4*)&Xf[(size_t)node * 128 + k0];
        float4 v1 = *(const float4*)&Xf[(size_t)node * 128 + k0 + 4];
        o.x = (u32)f2bf(v0.x) | ((u32)f2bf(v0.y) << 16);
        o.y = (u32)f2bf(v0.z) | ((u32)f2bf(v0.w) << 16);
        o.z = (u32)f2bf(v1.x) | ((u32)f2bf(v1.y) << 16);
        o.w = (u32)f2bf(v1.z) | ((u32)f2bf(v1.w) << 16);
      }
    }
    *(uint4*)&Xl[r * XP + k0] = o;
  }
  __syncthreads();

  const int w = tid >> 6, l = tid & 63;
  const int lr = l & 15, lg = l >> 4;
  f32x4 acc[NT];
#pragma unroll
  for (int t = 0; t < NT; ++t) acc[t] = f32x4{0.f, 0.f, 0.f, 0.f};

#pragma unroll
  for (int ks = 0; ks < 4; ++ks) {
    int kb = ks * 32 + lg * 8;
    bf16x8 a = *(const bf16x8*)&Xl[(w * 16 + lr) * XP + kb];
#pragma unroll
    for (int t = 0; t < NT; ++t) {
      bf16x8 b = *(const bf16x8*)&Wl[(t * 16 + lr) * XP + kb];
      acc[t] = __builtin_amdgcn_mfma_f32_16x16x32_bf16(a, b, acc[t], 0, 0, 0);
    }
  }

#pragma unroll
  for (int t = 0; t < NT; ++t)
#pragma unroll
    for (int j = 0; j < 4; ++j)
      Xl[(w * 16 + lg * 4 + j) * XP + t * 16 + lr] = f2bf(acc[t][j]);
  __syncthreads();

  if (F8OUT) {
    for (int i = tid; i < 64 * (DOUT / 8); i += 256) {
      int r = i / (DOUT / 8), c0 = (i % (DOUT / 8)) * 8;
      int node = base + r;
      if (node < n) {
        float f[8];
#pragma unroll
        for (int j = 0; j < 8; ++j) f[j] = bf1(Xl[r * XP + c0 + j]);
        int lo = 0, hi = 0;
        lo = __builtin_amdgcn_cvt_pk_fp8_f32(f[0], f[1], lo, false);
        lo = __builtin_amdgcn_cvt_pk_fp8_f32(f[2], f[3], lo, true);
        hi = __builtin_amdgcn_cvt_pk_fp8_f32(f[4], f[5], hi, false);
        hi = __builtin_amdgcn_cvt_pk_fp8_f32(f[6], f[7], hi, true);
        uint2 o = {(u32)lo, (u32)hi};
        *(uint2*)&Hf8[(size_t)node * DOUT + c0] = o;
      }
    }
  } else {
    for (int i = tid; i < 64 * (DOUT / 8); i += 256) {
      int r = i / (DOUT / 8), k0 = (i % (DOUT / 8)) * 8;
      int node = base + r;
      if (node < n)
        *(uint4*)&HfB[(size_t)node * DOUT + k0] = *(const uint4*)&Xl[r * XP + k0];
    }
  }

  int row = tid >> 2, quad = tid & 3;
  int node = base + row;
  if (NH == 8) {
#pragma unroll
    for (int h2 = 0; h2 < 2; ++h2) {
      int h = quad * 2 + h2;
      float ps = 0.f, pd = 0.f;
#pragma unroll
      for (int i2 = 0; i2 < 16; ++i2) {
        float hv = bf1(Xl[row * XP + h * 16 + i2]);
        ps = fmaf(hv, AsL[h * 16 + i2], ps);
        pd = fmaf(hv, AdL[h * 16 + i2], pd);
      }
      if (node < n) {
        als[node * 8 + h] = ps;
        ald[node * 8 + h] = pd;
      }
    }
  } else {
    float ps = 0.f, pd = 0.f;
#pragma unroll
    for (int i2 = 0; i2 < 16; ++i2) {
      float hv = bf1(Xl[row * XP + quad * 16 + i2]);
      ps = fmaf(hv, AsL[quad * 16 + i2], ps);
      pd = fmaf(hv, AdL[quad * 16 + i2], pd);
    }
    ps += __shfl_xor(ps, 1, 64);
    ps += __shfl_xor(ps, 2, 64);
    pd += __shfl_xor(pd, 1, 64);
    pd += __shfl_xor(pd, 2, 64);
    if (quad == 0 && node < n) {
      als[node] = ps;
      ald[node] = pd;
    }
  }
}

// ================= CSR build (once per call, reused 3x) ======================
__global__ __launch_bounds__(256) void deg_kernel(
    const int* __restrict__ ei, u32* __restrict__ deg, int E, int n,
    int nper, int chunk) {
  const int lo = (blockIdx.x & 7) * nper;
  const int hi = min(lo + nper, n);
  const int e0 = (blockIdx.x >> 3) * chunk;
  const int e1 = min(e0 + chunk, E + n);
  for (int e = e0 + (int)threadIdx.x; e < e1; e += 256) {
    int d = (e < E) ? ei[E + e] : (e - E);
    if (d >= lo && d < hi) atomicAdd(&deg[d], 1u);
  }
}

__global__ __launch_bounds__(1024) void scan1_kernel(const u32* __restrict__ deg,
                                                     u32* __restrict__ offs,
                                                     u32* __restrict__ bsum, int n) {
  __shared__ u32 tmp[1024];
  int t = threadIdx.x, i = blockIdx.x * 1024 + t;
  u32 v = (i < n) ? deg[i] : 0u;
  tmp[t] = v;
  __syncthreads();
  for (int off = 1; off < 1024; off <<= 1) {
    u32 a = (t >= off) ? tmp[t - off] : 0u;
    __syncthreads();
    tmp[t] += a;
    __syncthreads();
  }
  if (i < n) offs[i] = tmp[t] - v;
  if (t == 1023) bsum[blockIdx.x] = tmp[t];
}

// scan2+scan3 merged: each block reduces raw bsum[0..blockIdx) itself.
__global__ __launch_bounds__(1024) void scan23_kernel(
    u32* __restrict__ offs, const u32* __restrict__ bsum,
    u32* __restrict__ cursor, int n, u32 total, int nb) {
  __shared__ u32 tmp[1024];
  int t = threadIdx.x;
  tmp[t] = (t < nb && t < (int)blockIdx.x) ? bsum[t] : 0u;
  __syncthreads();
#pragma unroll
  for (int off = 512; off > 0; off >>= 1) {
    if (t < off) tmp[t] += tmp[t + off];
    __syncthreads();
  }
  u32 prefix = tmp[0];
  int i = blockIdx.x * 1024 + t;
  if (i < n) {
    u32 v = offs[i] + prefix;
    offs[i] = v;
    cursor[i] = v;
  }
  if (i == 0) offs[n] = total;
}

// XCD-partitioned fill: single-XCD ownership of csr/cursor lines.
__global__ __launch_bounds__(256) void fill_kernel(
    const int* __restrict__ ei, u32* __restrict__ cursor,
    int* __restrict__ csr_src, int E, int n, int nper, int chunk) {
  const int lo = (blockIdx.x & 7) * nper;
  const int hi = min(lo + nper, n);
  const int e0 = (blockIdx.x >> 3) * chunk;
  const int e1 = min(e0 + chunk, E + n);
  for (int e = e0 + (int)threadIdx.x; e < e1; e += 256) {
    int d = (e < E) ? ei[E + e] : (e - E);
    if (d >= lo && d < hi) {
      int s = (e < E) ? ei[e] : d;
      u32 pos = atomicAdd(&cursor[d], 1u);
      csr_src[pos] = s;
    }
  }
}

// ===== gather, DF=128, 8 heads, fp8 H, pk-ops, octet alpha, LN+ReLU =========
__global__ __launch_bounds__(256) void gat_gather128(
    const u32* __restrict__ offs, const int* __restrict__ csr,
    const float* __restrict__ als, const float* __restrict__ ald,
    const u8* __restrict__ Hf8, const float* __restrict__ bias,
    const float* __restrict__ g, const float* __restrict__ b,
    u16* __restrict__ outp, int n) {
  int d = blockIdx.x * 4 + (threadIdx.x >> 6);
  if (d >= n) return;
  const int lane = threadIdx.x & 63;
  const int h = lane >> 3;
  const float adv = ald[d * 8 + h];
  const u16* HfP = (const u16*)Hf8;  // fp8 feats {2l,2l+1} at s*64+l
  f32x2 acc2 = {0.f, 0.f};
  float lsum = 0.f;

  u32 k0 = offs[d], k1 = offs[d + 1], k = k0;
  for (; k + 8 <= k1; k += 8) {
    int s[8];
#pragma unroll
    for (int i = 0; i < 8; ++i) s[i] = csr[k + i];
    u16 w[8];
#pragma unroll
    for (int i = 0; i < 8; ++i) w[i] = HfP[(u32)s[i] * 64 + lane];
    int smine = csr[k + (lane & 7)];
    float v = als[smine * 8 + h] + adv;
    v = fmaxf(v, LRELU_SLOPE * v);
    float pm = __expf(v);
#pragma unroll
    for (int i = 0; i < 8; ++i) {
      float p = __shfl(pm, i, 8);
      lsum += p;
      f32x2 hw = __builtin_amdgcn_cvt_pk_f32_fp8((int)w[i], false);
      f32x2 pv = {p, p};
      acc2 = pv * hw + acc2;  // fp-contract -> v_pk_fma_f32
    }
  }
  if (k + 4 <= k1) {
    int s[4];
    float a[4];
    u16 w[4];
#pragma unroll
    for (int i = 0; i < 4; ++i) s[i] = csr[k + i];
#pragma unroll
    for (int i = 0; i < 4; ++i) {
      a[i] = als[s[i] * 8 + h];
      w[i] = HfP[(u32)s[i] * 64 + lane];
    }
#pragma unroll
    for (int i = 0; i < 4; ++i) {
      float v = a[i] + adv;
      v = fmaxf(v, LRELU_SLOPE * v);
      float p = __expf(v);
      lsum += p;
      f32x2 hw = __builtin_amdgcn_cvt_pk_f32_fp8((int)w[i], false);
      f32x2 pv = {p, p};
      acc2 = pv * hw + acc2;
    }
    k += 4;
  }
  for (; k < k1; ++k) {
    int s = csr[k];
    float aa = als[s * 8 + h];
    u16 w = HfP[(u32)s * 64 + lane];
    float v = aa + adv;
    v = fmaxf(v, LRELU_SLOPE * v);
    float p = __expf(v);
    lsum += p;
    f32x2 hw = __builtin_amdgcn_cvt_pk_f32_fp8((int)w, false);
    f32x2 pv = {p, p};
    acc2 = pv * hw + acc2;
  }

  float inv = 1.f / lsum;
  float2 bs = *(const float2*)&bias[2 * lane];
  float r0 = acc2.x * inv + bs.x, r1 = acc2.y * inv + bs.y;
  float ssum = r0 + r1;
#pragma unroll
  for (int off = 32; off > 0; off >>= 1) ssum += __shfl_xor(ssum, off, 64);
  float mu = ssum * (1.f / 128.f);
  float d0 = r0 - mu, d1 = r1 - mu;
  float q = d0 * d0 + d1 * d1;
#pragma unroll
  for (int off = 32; off > 0; off >>= 1) q += __shfl_xor(q, off, 64);
  float rstd = rsqrtf(q * (1.f / 128.f) + LN_EPS);
  float2 gg = *(const float2*)&g[2 * lane];
  float2 bb = *(const float2*)&b[2 * lane];
  float o0 = fmaxf(d0 * rstd * gg.x + bb.x, 0.f);
  float o1 = fmaxf(d1 * rstd * gg.y + bb.y, 0.f);
  u32 packed = (u32)f2bf(o0) | ((u32)f2bf(o1) << 16);
  *(u32*)&outp[(size_t)d * 128 + 2 * lane] = packed;
}

// ===== gather, DF=64, 1 head, bf16 H, octet alpha, log_softmax ==============
__global__ __launch_bounds__(256) void gat_gather64(
    const u32* __restrict__ offs, const int* __restrict__ csr,
    const float* __restrict__ als, const float* __restrict__ ald,
    const u16* __restrict__ HfB, const float* __restrict__ bias,
    float* __restrict__ outp, int n) {
  int d = blockIdx.x * 4 + (threadIdx.x >> 6);
  if (d >= n) return;
  const int lane = threadIdx.x & 63;
  const float adv = ald[d];
  float acc = 0.f, lsum = 0.f;
  u32 k0 = offs[d], k1 = offs[d + 1], k = k0;
  for (; k + 8 <= k1; k += 8) {
    int s[8];
#pragma unroll
    for (int i = 0; i < 8; ++i) s[i] = csr[k + i];
    u16 w[8];
#pragma unroll
    for (int i = 0; i < 8; ++i) w[i] = HfB[(size_t)s[i] * 64 + lane];
    int smine = csr[k + (lane & 7)];
    float v = als[smine] + adv;
    v = fmaxf(v, LRELU_SLOPE * v);
    float pm = __expf(v);
#pragma unroll
    for (int i = 0; i < 8; ++i) {
      float p = __shfl(pm, i, 8);
      lsum += p;
      acc = fmaf(p, bf1(w[i]), acc);
    }
  }
  if (k + 4 <= k1) {
    int s[4];
    float a[4];
    u16 w[4];
#pragma unroll
    for (int i = 0; i < 4; ++i) s[i] = csr[k + i];
#pragma unroll
    for (int i = 0; i < 4; ++i) {
      a[i] = als[s[i]];
      w[i] = HfB[(size_t)s[i] * 64 + lane];
    }
#pragma unroll
    for (int i = 0; i < 4; ++i) {
      float v = a[i] + adv;
      v = fmaxf(v, LRELU_SLOPE * v);
      float p = __expf(v);
      lsum += p;
      acc = fmaf(p, bf1(w[i]), acc);
    }
    k += 4;
  }
  for (; k < k1; ++k) {
    int s = csr[k];
    float v = als[s] + adv;
    v = fmaxf(v, LRELU_SLOPE * v);
    float p = __expf(v);
    lsum += p;
    acc = fmaf(p, bf1(HfB[(size_t)s * 64 + lane]), acc);
  }
  float v = acc / lsum + bias[lane];
  float mx = v;
#pragma unroll
  for (int off = 32; off > 0; off >>= 1) mx = fmaxf(mx, __shfl_xor(mx, off, 64));
  float e = __expf(v - mx);
  float ssum = e;
#pragma unroll
  for (int off = 32; off > 0; off >>= 1) ssum += __shfl_xor(ssum, off, 64);
  outp[(size_t)d * 64 + lane] = v - mx - __logf(ssum);
}

// ============================== launch ======================================
extern "C" void kernel_launch(void* const* d_in, const int* in_sizes, int n_in,
                              void* d_out, int out_size, void* d_ws,
                              size_t ws_size, hipStream_t stream) {
  const float* x    = (const float*)d_in[0];
  const int*   ei   = (const int*)d_in[1];
  const float* W0   = (const float*)d_in[2];
  const float* as0  = (const float*)d_in[3];
  const float* ad0  = (const float*)d_in[4];
  const float* b0   = (const float*)d_in[5];
  const float* W1   = (const float*)d_in[6];
  const float* as1  = (const float*)d_in[7];
  const float* ad1  = (const float*)d_in[8];
  const float* b1   = (const float*)d_in[9];
  const float* W2   = (const float*)d_in[10];
  const float* as2  = (const float*)d_in[11];
  const float* ad2  = (const float*)d_in[12];
  const float* b2   = (const float*)d_in[13];
  const float* ln1g = (const float*)d_in[14];
  const float* ln1b = (const float*)d_in[15];
  const float* ln2g = (const float*)d_in[16];
  const float* ln2b = (const float*)d_in[17];

  const int n = in_sizes[0] / 128;
  const int E = in_sizes[1] / 2;
  const int EP = E + n;

  u16* bufXb = (u16*)d_ws;                        // N*128 bf16 (LN outputs)
  u16* HfB   = bufXb + (size_t)n * 128;           // N*128 bf16 (layer-2 H)
  u8*  Hf8   = (u8*)(HfB + (size_t)n * 128);      // N*128 fp8 (layers 0/1 H)
  u16* Wt0   = (u16*)(Hf8 + (size_t)n * 128);     // 128*128
  u16* Wt1   = Wt0 + 16384;
  u16* Wt2   = Wt1 + 16384;                       // 64*128
  float* als = (float*)(Wt2 + 8192);              // N*8
  float* ald = als + (size_t)n * 8;
  u32* deg    = (u32*)(ald + (size_t)n * 8);
  u32* offs   = deg + n;
  u32* cursor = offs + (n + 1);
  u32* bsum   = cursor + n;
  int* csr    = (int*)(bsum + 1024);

  const dim3 blk(256);
  const int gFeat = (n + 63) / 64;
  const int gGath = (n + 3) / 4;
  const int nb = (n + 1023) / 1024;
  const int SEGS = 256;
  const int nper = (n + 7) / 8;
  const int chunk = (EP + SEGS - 1) / SEGS;

  // ---- CSR build + W convert (deg zeroing fused into wcvt) ----
  wcvt_kernel<<<160, blk, 0, stream>>>(W0, W1, W2, Wt0, Wt1, Wt2, deg, n);
  deg_kernel<<<8 * SEGS, blk, 0, stream>>>(ei, deg, E, n, nper, chunk);
  scan1_kernel<<<nb, 1024, 0, stream>>>(deg, offs, bsum, n);
  scan23_kernel<<<nb, 1024, 0, stream>>>(offs, bsum, cursor, n, (u32)EP, nb);
  fill_kernel<<<8 * SEGS, blk, 0, stream>>>(ei, cursor, csr, E, n, nper, chunk);

  // ---- conv0 + LN1 + ReLU ----
  feat_mfma<128, 8, false, true><<<gFeat, blk, 0, stream>>>(
      x, Wt0, as0, ad0, HfB, Hf8, als, ald, n);
  gat_gather128<<<gGath, blk, 0, stream>>>(
      offs, csr, als, ald, Hf8, b0, ln1g, ln1b, bufXb, n);

  // ---- conv1 + LN2 + ReLU ----
  feat_mfma<128, 8, true, true><<<gFeat, blk, 0, stream>>>(
      bufXb, Wt1, as1, ad1, HfB, Hf8, als, ald, n);
  gat_gather128<<<gGath, blk, 0, stream>>>(
      offs, csr, als, ald, Hf8, b1, ln2g, ln2b, bufXb, n);

  // ---- conv2 + log_softmax (bf16 H, fp32 accum) ----
  feat_mfma<64, 1, true, false><<<gFeat, blk, 0, stream>>>(
      bufXb, Wt2, as2, ad2, HfB, Hf8, als, ald, n);
  gat_gather64<<<gGath, blk, 0, stream>>>(
      offs, csr, als, ald, HfB, b2, (float*)d_out, n);
}

// Round 11
// 432.094 us; speedup vs baseline: 1.2951x; 1.2123x over previous
//
#include <hip/hip_runtime.h>

// GAT 3-layer forward — Round 11:
//  * gathers restructured half-wave-per-dst (32 lanes/dst, u32/lane): ~1.8x
//    fewer wave-instrs per (dst,edge) + 2 independent edge streams per wave
//    (2x MLP). Quad-local alpha producers, 1 shfl/edge. Bit-identical math.
//  * CSR: deg pass stores rank[e]=atomicAdd(deg[dst],1) (single unpartitioned
//    pass; fabric-side atomics don't ping-pong); fill uses offs[d]+rank[e],
//    NO atomics (keeps XCD write partition). cursor buffer dropped.
//
// Workspace (~86 MB): bufXb u16[N*128] | HfB u16[N*128] | Hf8 u8[N*128]
//   | Wt0/1/2 | als f32[N*8] | ald f32[N*8] | deg u32[N] | offs u32[N+1]
//   | bsum u32[1024] | csr i32[E+N] | rank u32[E+N]

#define LRELU_SLOPE 0.2f
#define LN_EPS 1e-5f
typedef unsigned int u32;
typedef unsigned short u16;
typedef unsigned char u8;
typedef float f32x2 __attribute__((ext_vector_type(2)));
typedef float f32x4 __attribute__((ext_vector_type(4)));
typedef short bf16x8 __attribute__((ext_vector_type(8)));

__device__ __forceinline__ u16 f2bf(float f) {  // RNE float->bf16
  u32 u = __float_as_uint(f);
  return (u16)((u + 0x7FFFu + ((u >> 16) & 1u)) >> 16);
}
__device__ __forceinline__ float bflo(u32 w) { return __uint_as_float(w << 16); }
__device__ __forceinline__ float bfhi(u32 w) { return __uint_as_float(w & 0xFFFF0000u); }
__device__ __forceinline__ float bf1(u16 w) { return __uint_as_float((u32)w << 16); }

// ==== W convert+transpose (+ deg zeroing fused), once per call ===============
__global__ void wcvt_kernel(const float* __restrict__ W0,
                            const float* __restrict__ W1,
                            const float* __restrict__ W2,
                            u16* __restrict__ Wt0, u16* __restrict__ Wt1,
                            u16* __restrict__ Wt2, u32* __restrict__ deg, int n) {
  int i = blockIdx.x * 256 + threadIdx.x;
  if (i < 16384) {
    int k = i >> 7, c = i & 127;
    Wt0[c * 128 + k] = f2bf(W0[i]);
  } else if (i < 32768) {
    int j = i - 16384;
    int k = j >> 7, c = j & 127;
    Wt1[c * 128 + k] = f2bf(W1[j]);
  } else if (i < 40960) {
    int j = i - 32768;
    int k = j >> 6, c = j & 63;
    Wt2[c * 128 + k] = f2bf(W2[j]);
  }
  for (int j = i; j < n; j += 40960) deg[j] = 0u;  // fused memset
}

// ========= feat (MFMA): H = X@W, bf16/fp8 out, fused als/ald dots ============
template <int DOUT, int NH, bool XBF, bool F8OUT>
__global__ __launch_bounds__(256) void feat_mfma(
    const void* __restrict__ Xv, const u16* __restrict__ Wtg,
    const float* __restrict__ As, const float* __restrict__ Ad,
    u16* __restrict__ HfB, u8* __restrict__ Hf8,
    float* __restrict__ als, float* __restrict__ ald, int n) {
  constexpr int NT = DOUT / 16;
  constexpr int XP = 136;        // +8 pad: 2-way banks, free
  __shared__ u16 Wl[DOUT * XP];
  __shared__ u16 Xl[64 * XP];
  __shared__ float AsL[DOUT], AdL[DOUT];

  const int tid = threadIdx.x;
  const int base = blockIdx.x * 64;

  if (tid < DOUT) { AsL[tid] = As[tid]; AdL[tid] = Ad[tid]; }
  for (int i = tid; i < DOUT * 16; i += 256) {
    int c = i >> 4, k0 = (i & 15) * 8;
    *(uint4*)&Wl[c * XP + k0] = *(const uint4*)&Wtg[c * 128 + k0];
  }
  for (int i = tid; i < 64 * 16; i += 256) {
    int r = i >> 4, k0 = (i & 15) * 8;
    int node = base + r;
    uint4 o = uint4{0, 0, 0, 0};
    if (node < n) {
      if (XBF) {
        o = *(const uint4*)((const u16*)Xv + (size_t)node * 128 + k0);
      } else {
        const float* Xf = (const float*)Xv;
        float4 v0 = *(const float4*)&Xf[(size_t)node * 128 + k0];
        float4 v1 = *(const float4*)&Xf[(size_t)node * 128 + k0 + 4];
        o.x = (u32)f2bf(v0.x) | ((u32)f2bf(v0.y) << 16);
        o.y = (u32)f2bf(v0.z) | ((u32)f2bf(v0.w) << 16);
        o.z = (u32)f2bf(v1.x) | ((u32)f2bf(v1.y) << 16);
        o.w = (u32)f2bf(v1.z) | ((u32)f2bf(v1.w) << 16);
      }
    }
    *(uint4*)&Xl[r * XP + k0] = o;
  }
  __syncthreads();

  const int w = tid >> 6, l = tid & 63;
  const int lr = l & 15, lg = l >> 4;
  f32x4 acc[NT];
#pragma unroll
  for (int t = 0; t < NT; ++t) acc[t] = f32x4{0.f, 0.f, 0.f, 0.f};

#pragma unroll
  for (int ks = 0; ks < 4; ++ks) {
    int kb = ks * 32 + lg * 8;
    bf16x8 a = *(const bf16x8*)&Xl[(w * 16 + lr) * XP + kb];
#pragma unroll
    for (int t = 0; t < NT; ++t) {
      bf16x8 b = *(const bf16x8*)&Wl[(t * 16 + lr) * XP + kb];
      acc[t] = __builtin_amdgcn_mfma_f32_16x16x32_bf16(a, b, acc[t], 0, 0, 0);
    }
  }

#pragma unroll
  for (int t = 0; t < NT; ++t)
#pragma unroll
    for (int j = 0; j < 4; ++j)
      Xl[(w * 16 + lg * 4 + j) * XP + t * 16 + lr] = f2bf(acc[t][j]);
  __syncthreads();

  if (F8OUT) {
    for (int i = tid; i < 64 * (DOUT / 8); i += 256) {
      int r = i / (DOUT / 8), c0 = (i % (DOUT / 8)) * 8;
      int node = base + r;
      if (node < n) {
        float f[8];
#pragma unroll
        for (int j = 0; j < 8; ++j) f[j] = bf1(Xl[r * XP + c0 + j]);
        int lo = 0, hi = 0;
        lo = __builtin_amdgcn_cvt_pk_fp8_f32(f[0], f[1], lo, false);
        lo = __builtin_amdgcn_cvt_pk_fp8_f32(f[2], f[3], lo, true);
        hi = __builtin_amdgcn_cvt_pk_fp8_f32(f[4], f[5], hi, false);
        hi = __builtin_amdgcn_cvt_pk_fp8_f32(f[6], f[7], hi, true);
        uint2 o = {(u32)lo, (u32)hi};
        *(uint2*)&Hf8[(size_t)node * DOUT + c0] = o;
      }
    }
  } else {
    for (int i = tid; i < 64 * (DOUT / 8); i += 256) {
      int r = i / (DOUT / 8), k0 = (i % (DOUT / 8)) * 8;
      int node = base + r;
      if (node < n)
        *(uint4*)&HfB[(size_t)node * DOUT + k0] = *(const uint4*)&Xl[r * XP + k0];
    }
  }

  int row = tid >> 2, quad = tid & 3;
  int node = base + row;
  if (NH == 8) {
#pragma unroll
    for (int h2 = 0; h2 < 2; ++h2) {
      int h = quad * 2 + h2;
      float ps = 0.f, pd = 0.f;
#pragma unroll
      for (int i2 = 0; i2 < 16; ++i2) {
        float hv = bf1(Xl[row * XP + h * 16 + i2]);
        ps = fmaf(hv, AsL[h * 16 + i2], ps);
        pd = fmaf(hv, AdL[h * 16 + i2], pd);
      }
      if (node < n) {
        als[node * 8 + h] = ps;
        ald[node * 8 + h] = pd;
      }
    }
  } else {
    float ps = 0.f, pd = 0.f;
#pragma unroll
    for (int i2 = 0; i2 < 16; ++i2) {
      float hv = bf1(Xl[row * XP + quad * 16 + i2]);
      ps = fmaf(hv, AsL[quad * 16 + i2], ps);
      pd = fmaf(hv, AdL[quad * 16 + i2], pd);
    }
    ps += __shfl_xor(ps, 1, 64);
    ps += __shfl_xor(ps, 2, 64);
    pd += __shfl_xor(pd, 1, 64);
    pd += __shfl_xor(pd, 2, 64);
    if (quad == 0 && node < n) {
      als[node] = ps;
      ald[node] = pd;
    }
  }
}

// ================= CSR build ================================================
// Histogram + per-edge rank capture (single pass; device atomics are
// fabric-side on MI355X so no XCD partition needed here).
__global__ void deg_kernel(const int* __restrict__ ei, u32* __restrict__ deg,
                           u32* __restrict__ rank, int E, int n) {
  int e = blockIdx.x * blockDim.x + threadIdx.x;
  if (e >= E + n) return;
  int d = (e < E) ? ei[E + e] : (e - E);
  rank[e] = atomicAdd(&deg[d], 1u);
}

__global__ __launch_bounds__(1024) void scan1_kernel(const u32* __restrict__ deg,
                                                     u32* __restrict__ offs,
                                                     u32* __restrict__ bsum, int n) {
  __shared__ u32 tmp[1024];
  int t = threadIdx.x, i = blockIdx.x * 1024 + t;
  u32 v = (i < n) ? deg[i] : 0u;
  tmp[t] = v;
  __syncthreads();
  for (int off = 1; off < 1024; off <<= 1) {
    u32 a = (t >= off) ? tmp[t - off] : 0u;
    __syncthreads();
    tmp[t] += a;
    __syncthreads();
  }
  if (i < n) offs[i] = tmp[t] - v;
  if (t == 1023) bsum[blockIdx.x] = tmp[t];
}

// scan2+scan3 merged: each block reduces raw bsum[0..blockIdx) itself.
__global__ __launch_bounds__(1024) void scan23_kernel(
    u32* __restrict__ offs, const u32* __restrict__ bsum, int n, u32 total,
    int nb) {
  __shared__ u32 tmp[1024];
  int t = threadIdx.x;
  tmp[t] = (t < nb && t < (int)blockIdx.x) ? bsum[t] : 0u;
  __syncthreads();
#pragma unroll
  for (int off = 512; off > 0; off >>= 1) {
    if (t < off) tmp[t] += tmp[t + off];
    __syncthreads();
  }
  u32 prefix = tmp[0];
  int i = blockIdx.x * 1024 + t;
  if (i < n) offs[i] += prefix;
  if (i == 0) offs[n] = total;
}

// XCD-partitioned fill, atomic-free (pos = offs[d] + rank[e]).
__global__ __launch_bounds__(256) void fill_kernel(
    const int* __restrict__ ei, const u32* __restrict__ offs,
    const u32* __restrict__ rank, int* __restrict__ csr_src, int E, int n,
    int nper, int chunk) {
  const int lo = (blockIdx.x & 7) * nper;
  const int hi = min(lo + nper, n);
  const int e0 = (blockIdx.x >> 3) * chunk;
  const int e1 = min(e0 + chunk, E + n);
  for (int e = e0 + (int)threadIdx.x; e < e1; e += 256) {
    int d = (e < E) ? ei[E + e] : (e - E);
    if (d >= lo && d < hi) {
      int s = (e < E) ? ei[e] : d;
      csr_src[offs[d] + rank[e]] = s;
    }
  }
}

// ===== gather, DF=128, 8 heads, fp8 H, half-wave/dst, LN+ReLU ===============
// 32 lanes per dst; lane owns feats {4l..4l+3} (one u32 of 4 fp8), head = l>>2.
// 8-edge block: lane (4h+j) computes alphas for edges {2j,2j+1}; consumers
// pull with __shfl(.., i>>1, 4). Bit-identical to the 64-lane version.
__global__ __launch_bounds__(256) void gat_gather128(
    const u32* __restrict__ offs, const int* __restrict__ csr,
    const float* __restrict__ als, const float* __restrict__ ald,
    const u8* __restrict__ Hf8, const float* __restrict__ bias,
    const float* __restrict__ g, const float* __restrict__ b,
    u16* __restrict__ outp, int n) {
  int d = blockIdx.x * 8 + (threadIdx.x >> 5);
  if (d >= n) return;
  const int l = threadIdx.x & 31;
  const int h = l >> 2;          // head of feats 4l..4l+3
  const int jgrp = l & 3;        // producer slot within head quad
  const float adv = ald[d * 8 + h];
  const u32* HfW = (const u32*)Hf8;  // word index = s*32 + l
  f32x2 accA = {0.f, 0.f}, accB = {0.f, 0.f};
  float lsum = 0.f;

  u32 k0 = offs[d], k1 = offs[d + 1], k = k0;
  for (; k + 8 <= k1; k += 8) {
    int s[8];
#pragma unroll
    for (int i = 0; i < 8; ++i) s[i] = csr[k + i];
    u32 w[8];
#pragma unroll
    for (int i = 0; i < 8; ++i) w[i] = HfW[(u32)s[i] * 32 + l];
    int sA = csr[k + 2 * jgrp];
    int sB = csr[k + 2 * jgrp + 1];
    float vA = als[sA * 8 + h] + adv;
    vA = fmaxf(vA, LRELU_SLOPE * vA);
    float pA = __expf(vA);
    float vB = als[sB * 8 + h] + adv;
    vB = fmaxf(vB, LRELU_SLOPE * vB);
    float pB = __expf(vB);
#pragma unroll
    for (int i = 0; i < 8; ++i) {
      float p = __shfl((i & 1) ? pB : pA, i >> 1, 4);
      lsum += p;
      f32x2 pv = {p, p};
      accA = pv * __builtin_amdgcn_cvt_pk_f32_fp8((int)w[i], false) + accA;
      accB = pv * __builtin_amdgcn_cvt_pk_f32_fp8((int)w[i], true) + accB;
    }
  }
  if (k + 4 <= k1) {
    int s[4];
#pragma unroll
    for (int i = 0; i < 4; ++i) s[i] = csr[k + i];
    u32 w[4];
#pragma unroll
    for (int i = 0; i < 4; ++i) w[i] = HfW[(u32)s[i] * 32 + l];
    int sA = csr[k + jgrp];
    float vA = als[sA * 8 + h] + adv;
    vA = fmaxf(vA, LRELU_SLOPE * vA);
    float pA = __expf(vA);
#pragma unroll
    for (int i = 0; i < 4; ++i) {
      float p = __shfl(pA, i, 4);
      lsum += p;
      f32x2 pv = {p, p};
      accA = pv * __builtin_amdgcn_cvt_pk_f32_fp8((int)w[i], false) + accA;
      accB = pv * __builtin_amdgcn_cvt_pk_f32_fp8((int)w[i], true) + accB;
    }
    k += 4;
  }
  for (; k < k1; ++k) {
    int s = csr[k];
    float v = als[s * 8 + h] + adv;
    v = fmaxf(v, LRELU_SLOPE * v);
    float p = __expf(v);
    u32 w = HfW[(u32)s * 32 + l];
    lsum += p;
    f32x2 pv = {p, p};
    accA = pv * __builtin_amdgcn_cvt_pk_f32_fp8((int)w, false) + accA;
    accB = pv * __builtin_amdgcn_cvt_pk_f32_fp8((int)w, true) + accB;
  }

  float inv = 1.f / lsum;
  float4 bs = *(const float4*)&bias[4 * l];
  float r0 = accA.x * inv + bs.x, r1 = accA.y * inv + bs.y;
  float r2 = accB.x * inv + bs.z, r3 = accB.y * inv + bs.w;
  // LayerNorm over 128 across the half-wave (width-32 reduces)
  float ssum = r0 + r1 + r2 + r3;
#pragma unroll
  for (int off = 16; off > 0; off >>= 1) ssum += __shfl_xor(ssum, off, 32);
  float mu = ssum * (1.f / 128.f);
  float d0 = r0 - mu, d1 = r1 - mu, d2 = r2 - mu, d3 = r3 - mu;
  float q = d0 * d0 + d1 * d1 + d2 * d2 + d3 * d3;
#pragma unroll
  for (int off = 16; off > 0; off >>= 1) q += __shfl_xor(q, off, 32);
  float rstd = rsqrtf(q * (1.f / 128.f) + LN_EPS);
  float4 gg = *(const float4*)&g[4 * l];
  float4 bb = *(const float4*)&b[4 * l];
  float o0 = fmaxf(d0 * rstd * gg.x + bb.x, 0.f);
  float o1 = fmaxf(d1 * rstd * gg.y + bb.y, 0.f);
  float o2 = fmaxf(d2 * rstd * gg.z + bb.z, 0.f);
  float o3 = fmaxf(d3 * rstd * gg.w + bb.w, 0.f);
  uint2 packed = {(u32)f2bf(o0) | ((u32)f2bf(o1) << 16),
                  (u32)f2bf(o2) | ((u32)f2bf(o3) << 16)};
  *(uint2*)&outp[(size_t)d * 128 + 4 * l] = packed;
}

// ===== gather, DF=64, 1 head, bf16 H, half-wave/dst, log_softmax ============
// 32 lanes per dst; lane owns feats {2l,2l+1} (one u32 of 2 bf16).
__global__ __launch_bounds__(256) void gat_gather64(
    const u32* __restrict__ offs, const int* __restrict__ csr,
    const float* __restrict__ als, const float* __restrict__ ald,
    const u16* __restrict__ HfB, const float* __restrict__ bias,
    float* __restrict__ outp, int n) {
  int d = blockIdx.x * 8 + (threadIdx.x >> 5);
  if (d >= n) return;
  const int l = threadIdx.x & 31;
  const float adv = ald[d];
  const u32* HfW = (const u32*)HfB;  // word index = s*32 + l
  f32x2 acc2 = {0.f, 0.f};
  float lsum = 0.f;
  u32 k0 = offs[d], k1 = offs[d + 1], k = k0;
  for (; k + 8 <= k1; k += 8) {
    int s[8];
#pragma unroll
    for (int i = 0; i < 8; ++i) s[i] = csr[k + i];
    u32 w[8];
#pragma unroll
    for (int i = 0; i < 8; ++i) w[i] = HfW[(u32)s[i] * 32 + l];
    int sm = csr[k + (l & 7)];
    float v = als[sm] + adv;
    v = fmaxf(v, LRELU_SLOPE * v);
    float pm = __expf(v);
#pragma unroll
    for (int i = 0; i < 8; ++i) {
      float p = __shfl(pm, i, 8);
      lsum += p;
      f32x2 hw = {bflo(w[i]), bfhi(w[i])};
      f32x2 pv = {p, p};
      acc2 = pv * hw + acc2;
    }
  }
  if (k + 4 <= k1) {
    int s[4];
#pragma unroll
    for (int i = 0; i < 4; ++i) s[i] = csr[k + i];
    u32 w[4];
#pragma unroll
    for (int i = 0; i < 4; ++i) w[i] = HfW[(u32)s[i] * 32 + l];
    int sm = csr[k + (l & 3)];
    float v = als[sm] + adv;
    v = fmaxf(v, LRELU_SLOPE * v);
    float pm = __expf(v);
#pragma unroll
    for (int i = 0; i < 4; ++i) {
      float p = __shfl(pm, i, 4);
      lsum += p;
      f32x2 hw = {bflo(w[i]), bfhi(w[i])};
      f32x2 pv = {p, p};
      acc2 = pv * hw + acc2;
    }
    k += 4;
  }
  for (; k < k1; ++k) {
    int s = csr[k];
    float v = als[s] + adv;
    v = fmaxf(v, LRELU_SLOPE * v);
    float p = __expf(v);
    u32 w = HfW[(u32)s * 32 + l];
    lsum += p;
    f32x2 hw = {bflo(w), bfhi(w)};
    f32x2 pv = {p, p};
    acc2 = pv * hw + acc2;
  }
  float inv = 1.f / lsum;
  float2 bs = *(const float2*)&bias[2 * l];
  float r0 = acc2.x * inv + bs.x, r1 = acc2.y * inv + bs.y;
  // log_softmax over 64 across the half-wave
  float mx = fmaxf(r0, r1);
#pragma unroll
  for (int off = 16; off > 0; off >>= 1) mx = fmaxf(mx, __shfl_xor(mx, off, 32));
  float e = __expf(r0 - mx) + __expf(r1 - mx);
#pragma unroll
  for (int off = 16; off > 0; off >>= 1) e += __shfl_xor(e, off, 32);
  float lse = __logf(e);
  *(float2*)&outp[(size_t)d * 64 + 2 * l] =
      float2{r0 - mx - lse, r1 - mx - lse};
}

// ============================== launch ======================================
extern "C" void kernel_launch(void* const* d_in, const int* in_sizes, int n_in,
                              void* d_out, int out_size, void* d_ws,
                              size_t ws_size, hipStream_t stream) {
  const float* x    = (const float*)d_in[0];
  const int*   ei   = (const int*)d_in[1];
  const float* W0   = (const float*)d_in[2];
  const float* as0  = (const float*)d_in[3];
  const float* ad0  = (const float*)d_in[4];
  const float* b0   = (const float*)d_in[5];
  const float* W1   = (const float*)d_in[6];
  const float* as1  = (const float*)d_in[7];
  const float* ad1  = (const float*)d_in[8];
  const float* b1   = (const float*)d_in[9];
  const float* W2   = (const float*)d_in[10];
  const float* as2  = (const float*)d_in[11];
  const float* ad2  = (const float*)d_in[12];
  const float* b2   = (const float*)d_in[13];
  const float* ln1g = (const float*)d_in[14];
  const float* ln1b = (const float*)d_in[15];
  const float* ln2g = (const float*)d_in[16];
  const float* ln2b = (const float*)d_in[17];

  const int n = in_sizes[0] / 128;
  const int E = in_sizes[1] / 2;
  const int EP = E + n;

  u16* bufXb = (u16*)d_ws;                        // N*128 bf16 (LN outputs)
  u16* HfB   = bufXb + (size_t)n * 128;           // N*128 bf16 (layer-2 H)
  u8*  Hf8   = (u8*)(HfB + (size_t)n * 128);      // N*128 fp8 (layers 0/1 H)
  u16* Wt0   = (u16*)(Hf8 + (size_t)n * 128);     // 128*128
  u16* Wt1   = Wt0 + 16384;
  u16* Wt2   = Wt1 + 16384;                       // 64*128
  float* als = (float*)(Wt2 + 8192);              // N*8
  float* ald = als + (size_t)n * 8;
  u32* deg   = (u32*)(ald + (size_t)n * 8);
  u32* offs  = deg + n;                           // n+1
  u32* bsum  = offs + (n + 1);                    // 1024
  int* csr   = (int*)(bsum + 1024);               // E+n
  u32* rank  = (u32*)(csr + EP);                  // E+n

  const dim3 blk(256);
  const int gFeat = (n + 63) / 64;
  const int gGath = (n + 7) / 8;
  const int gEdge = (EP + 255) / 256;
  const int nb = (n + 1023) / 1024;
  const int SEGS = 256;
  const int nper = (n + 7) / 8;
  const int chunk = (EP + SEGS - 1) / SEGS;

  // ---- CSR build + W convert ----
  wcvt_kernel<<<160, blk, 0, stream>>>(W0, W1, W2, Wt0, Wt1, Wt2, deg, n);
  deg_kernel<<<gEdge, blk, 0, stream>>>(ei, deg, rank, E, n);
  scan1_kernel<<<nb, 1024, 0, stream>>>(deg, offs, bsum, n);
  scan23_kernel<<<nb, 1024, 0, stream>>>(offs, bsum, n, (u32)EP, nb);
  fill_kernel<<<8 * SEGS, blk, 0, stream>>>(ei, offs, rank, csr, E, n, nper, chunk);

  // ---- conv0 + LN1 + ReLU ----
  feat_mfma<128, 8, false, true><<<gFeat, blk, 0, stream>>>(
      x, Wt0, as0, ad0, HfB, Hf8, als, ald, n);
  gat_gather128<<<gGath, blk, 0, stream>>>(
      offs, csr, als, ald, Hf8, b0, ln1g, ln1b, bufXb, n);

  // ---- conv1 + LN2 + ReLU ----
  feat_mfma<128, 8, true, true><<<gFeat, blk, 0, stream>>>(
      bufXb, Wt1, as1, ad1, HfB, Hf8, als, ald, n);
  gat_gather128<<<gGath, blk, 0, stream>>>(
      offs, csr, als, ald, Hf8, b1, ln2g, ln2b, bufXb, n);

  // ---- conv2 + log_softmax (bf16 H, fp32 accum) ----
  feat_mfma<64, 1, true, false><<<gFeat, blk, 0, stream>>>(
      bufXb, Wt2, as2, ad2, HfB, Hf8, als, ald, n);
  gat_gather64<<<gGath, blk, 0, stream>>>(
      offs, csr, als, ald, HfB, b2, (float*)d_out, n);
}